// Round 1
// baseline (4307.162 us; speedup 1.0000x reference)
//
#include <hip/hip_runtime.h>
#include <math.h>

constexpr int B_ = 4, C_ = 60, H_ = 384, W_ = 384;
constexpr int HW_ = H_ * W_;
constexpr int E_ = 120;
constexpr int NC_ = B_ * C_ * HW_;   // 35,389,440
constexpr int NE_ = B_ * E_ * HW_;   // 70,778,880

// ---------------------------------------------------------------------------
// Fused shift5 + conv1x1 (+BN) (+ReLU) (+residual) (+q-extract) kernel.
// Block: 256 threads = 64 pixels x 4 output-channel groups.
// LDS: CIN x 64 input tile (shift applied at load).
// ---------------------------------------------------------------------------
template<int CIN, int COUT, int GSH, bool RELU, bool BN, bool RESID, bool EXTRACT>
__global__ __launch_bounds__(256)
void conv_k(const float* __restrict__ in, const float* __restrict__ wt,
            const float* __restrict__ bias,
            const float* __restrict__ bng, const float* __restrict__ bnb,
            const float* __restrict__ bnm, const float* __restrict__ bnv,
            const float* __restrict__ resid, float* __restrict__ out,
            float* __restrict__ q0)
{
    constexpr int OPT = COUT / 4;
    __shared__ float tile[CIN * 64];
    const int tid = threadIdx.x;
    const int n0 = blockIdx.x * 64;        // 64 pixels per block, never crosses b
    const int b  = n0 / HW_;
    const int p0 = n0 - b * HW_;

    // stage input tile (shift5 applied per source channel)
    for (int l = tid; l < CIN * 64; l += 256) {
        const int c  = l >> 6, px = l & 63;
        const int p  = p0 + px;
        float v;
        if (GSH > 0) {
            const int h = p / W_;
            const int w = p - h * W_;
            const int grp = c / GSH;
            const int dh = (grp == 2) ? 1 : ((grp == 3) ? -1 : 0);
            const int dw = (grp == 0) ? 1 : ((grp == 1) ? -1 : 0);
            const int h2 = h + dh, w2 = w + dw;
            v = 0.f;
            if ((unsigned)h2 < (unsigned)H_ && (unsigned)w2 < (unsigned)W_)
                v = in[(b * CIN + c) * HW_ + h2 * W_ + w2];
        } else {
            v = in[(b * CIN + c) * HW_ + p];
        }
        tile[l] = v;
    }
    __syncthreads();

    const int og = __builtin_amdgcn_readfirstlane(tid >> 6);  // wave-uniform
    const int px = tid & 63;
    const int o0 = og * OPT;

    float acc[OPT];
    #pragma unroll
    for (int i = 0; i < OPT; ++i) acc[i] = 0.f;

    for (int c = 0; c < CIN; ++c) {
        const float xv = tile[c * 64 + px];
        #pragma unroll
        for (int i = 0; i < OPT; ++i)
            acc[i] = fmaf(wt[(o0 + i) * CIN + c], xv, acc[i]);
    }

    const int p = p0 + px;
    #pragma unroll
    for (int i = 0; i < OPT; ++i) {
        const int o = o0 + i;
        float r = acc[i] + bias[o];
        if (BN) {
            const float inv = bng[o] * rsqrtf(bnv[o] + 1e-5f);
            r = (r - bnm[o]) * inv + bnb[o];
        }
        if (RELU) r = fmaxf(r, 0.f);
        const int oidx = (b * COUT + o) * HW_ + p;
        if (RESID) r += resid[oidx];
        out[oidx] = r;
        if (EXTRACT) {
            // keep q-channels (first 20 of each 40-channel window group) for
            // attention recompute in gmsa_shared
            const int wi = o / 40, rr = o - wi * 40;
            if (rr < 20)
                q0[(b * 60 + wi * 20 + rr) * HW_ + p] = r;
        }
    }
}

// ---------------------------------------------------------------------------
// Window attention: per thread = one attention row (one window position).
// q/v staged in LDS; online softmax; 20-channel accumulator.
// Handles both gmsa_first (q,v from xp0) and gmsa_shared (q from Q0, v from xp1)
// via channel-base/stride arguments.
// ---------------------------------------------------------------------------
template<int WS, int NW>
__global__ __launch_bounds__(NW * WS * WS)
void attn_k(const float* __restrict__ qsrc, int qC, int qbase,
            const float* __restrict__ vsrc, int vC, int vbase,
            float* __restrict__ out, int obase)
{
    constexpr int P     = WS * WS;
    constexpr int S     = WS / 2;
    constexpr int WGX   = W_ / WS;
    constexpr int WGY   = H_ / WS;
    constexpr int PITCH = 24;               // 96B row pitch: b128-aligned
    __shared__ float qt[NW * P * PITCH];
    __shared__ float vt[NW * P * PITCH];

    const int tid  = threadIdx.x;
    const int win  = tid / P;
    const int pos  = tid - win * P;
    const int gw   = blockIdx.x * NW + win;
    const int b    = gw / (WGY * WGX);
    const int rwin = gw - b * (WGY * WGX);
    const int wh   = rwin / WGX;
    const int ww   = rwin - wh * WGX;
    const int r    = pos / WS;
    const int c    = pos - r * WS;
    int hs = wh * WS + r + S; if (hs >= H_) hs -= H_;   // roll by -S (read side)
    int wd = ww * WS + c + S; if (wd >= W_) wd -= W_;

    // each thread stages its own row's 20 q + 20 v channels
    #pragma unroll
    for (int ch = 0; ch < 20; ++ch)
        qt[(win * P + pos) * PITCH + ch] =
            qsrc[(b * qC + qbase + ch) * HW_ + hs * W_ + wd];
    #pragma unroll
    for (int ch = 0; ch < 20; ++ch)
        vt[(win * P + pos) * PITCH + ch] =
            vsrc[(b * vC + vbase + ch) * HW_ + hs * W_ + wd];
    __syncthreads();

    float qr[20];
    #pragma unroll
    for (int i = 0; i < 20; ++i) qr[i] = qt[(win * P + pos) * PITCH + i];

    float m = -INFINITY, lsum = 0.f;
    float acc[20];
    #pragma unroll
    for (int i = 0; i < 20; ++i) acc[i] = 0.f;

    for (int j = 0; j < P; ++j) {
        const float* qj = &qt[(win * P + j) * PITCH];
        float s = 0.f;
        #pragma unroll
        for (int i = 0; i < 20; ++i) s = fmaf(qr[i], qj[i], s);
        const float nm = fmaxf(m, s);
        const float f  = __expf(m - nm);    // first iter: exp(-inf) = 0
        const float e  = __expf(s - nm);
        lsum = lsum * f + e;
        const float* vj = &vt[(win * P + j) * PITCH];
        #pragma unroll
        for (int i = 0; i < 20; ++i) acc[i] = fmaf(e, vj[i], acc[i] * f);
        m = nm;
    }
    const float inv = 1.f / lsum;
    #pragma unroll
    for (int i = 0; i < 20; ++i)
        out[(b * 60 + obase + i) * HW_ + hs * W_ + wd] = acc[i] * inv;
}

// ---------------------------------------------------------------------------
extern "C" void kernel_launch(void* const* d_in, const int* in_sizes, int n_in,
                              void* d_out, int out_size, void* d_ws, size_t ws_size,
                              hipStream_t stream)
{
    const float* x     = (const float*)d_in[0];
    const float* l0w0  = (const float*)d_in[1];
    const float* l0b0  = (const float*)d_in[2];
    const float* l0w1  = (const float*)d_in[3];
    const float* l0b1  = (const float*)d_in[4];
    const float* g0piw = (const float*)d_in[5];
    const float* g0pib = (const float*)d_in[6];
    const float* g0bng = (const float*)d_in[7];
    const float* g0bnb = (const float*)d_in[8];
    const float* g0bnm = (const float*)d_in[9];
    const float* g0bnv = (const float*)d_in[10];
    const float* g0pow = (const float*)d_in[11];
    const float* g0pob = (const float*)d_in[12];
    const float* l1w0  = (const float*)d_in[13];
    const float* l1b0  = (const float*)d_in[14];
    const float* l1w1  = (const float*)d_in[15];
    const float* l1b1  = (const float*)d_in[16];
    const float* g1piw = (const float*)d_in[17];
    const float* g1pib = (const float*)d_in[18];
    const float* g1bng = (const float*)d_in[19];
    const float* g1bnb = (const float*)d_in[20];
    const float* g1bnm = (const float*)d_in[21];
    const float* g1bnv = (const float*)d_in[22];
    const float* g1pow = (const float*)d_in[23];
    const float* g1pob = (const float*)d_in[24];

    // workspace layout: A(120ch) | Q0(60ch) | CC(60ch)  = 566 MB
    float* A    = (float*)d_ws;
    float* Q0   = A + NE_;
    float* CC   = Q0 + NC_;
    float* OUTF = (float*)d_out;   // doubles as ys0 / xp1 scratch, final output

    dim3 blk(256);
    dim3 gconv(B_ * HW_ / 64);     // 9216 blocks

    // S1: lfe0 hidden = relu(conv(shift5(x)))
    conv_k<60,120,12,true,false,false,false><<<gconv,blk,0,stream>>>(
        x, l0w0, l0b0, nullptr,nullptr,nullptr,nullptr, nullptr, A, nullptr);
    // S2: x1 = conv(shift5(hidden)) + x
    conv_k<120,60,24,false,false,true,false><<<gconv,blk,0,stream>>>(
        A, l0w1, l0b1, nullptr,nullptr,nullptr,nullptr, x, CC, nullptr);
    // S3: xp0 = BN(pi0(x1)); also extract q-channels into Q0
    conv_k<60,120,0,false,true,false,true><<<gconv,blk,0,stream>>>(
        CC, g0piw, g0pib, g0bng,g0bnb,g0bnm,g0bnv, nullptr, A, Q0);
    // S4: gmsa_first attention -> ys0 (in d_out scratch)
    attn_k<4,16><<<dim3(36864/16),dim3(256),0,stream>>>(A,120,0,   A,120,20,  OUTF, 0);
    attn_k<8, 4><<<dim3( 9216/4 ),dim3(256),0,stream>>>(A,120,40,  A,120,60,  OUTF,20);
    attn_k<12,1><<<dim3( 4096   ),dim3(144),0,stream>>>(A,120,80,  A,120,100, OUTF,40);
    // S5: x2 = po0(ys0) + x1   (in-place residual into CC)
    conv_k<60,60,0,false,false,true,false><<<gconv,blk,0,stream>>>(
        OUTF, g0pow, g0pob, nullptr,nullptr,nullptr,nullptr, CC, CC, nullptr);
    // S6: lfe1 hidden = relu(conv(shift5(x2)))
    conv_k<60,120,12,true,false,false,false><<<gconv,blk,0,stream>>>(
        CC, l1w0, l1b0, nullptr,nullptr,nullptr,nullptr, nullptr, A, nullptr);
    // S7: x3 = conv(shift5(hidden)) + x2
    conv_k<120,60,24,false,false,true,false><<<gconv,blk,0,stream>>>(
        A, l1w1, l1b1, nullptr,nullptr,nullptr,nullptr, CC, CC, nullptr);
    // S8: xp1 = BN(pi1(x3))  (into d_out scratch)
    conv_k<60,60,0,false,true,false,false><<<gconv,blk,0,stream>>>(
        CC, g1piw, g1pib, g1bng,g1bnb,g1bnm,g1bnv, nullptr, OUTF, nullptr);
    // S9: gmsa_shared attention (atn recomputed from Q0) -> ys1 (in A)
    attn_k<4,16><<<dim3(36864/16),dim3(256),0,stream>>>(Q0,60,0,  OUTF,60,0,  A, 0);
    attn_k<8, 4><<<dim3( 9216/4 ),dim3(256),0,stream>>>(Q0,60,20, OUTF,60,20, A,20);
    attn_k<12,1><<<dim3( 4096   ),dim3(144),0,stream>>>(Q0,60,40, OUTF,60,40, A,40);
    // S10: out = po1(ys1) + x3
    conv_k<60,60,0,false,false,true,false><<<gconv,blk,0,stream>>>(
        A, g1pow, g1pob, nullptr,nullptr,nullptr,nullptr, CC, OUTF, nullptr);
}

// Round 2
// 1764.691 us; speedup vs baseline: 2.4407x; 2.4407x over previous
//
#include <hip/hip_runtime.h>
#include <math.h>

constexpr int B_ = 4, C_ = 60, H_ = 384, W_ = 384;
constexpr int HW_ = H_ * W_;
constexpr int E_ = 120;
constexpr int NC_ = B_ * C_ * HW_;   // 35,389,440
constexpr int NE_ = B_ * E_ * HW_;   // 70,778,880

typedef __attribute__((ext_vector_type(8))) short short8;
typedef __attribute__((ext_vector_type(4))) float f32x4;

__device__ __forceinline__ unsigned short f2b(float f) {
    unsigned u = __builtin_bit_cast(unsigned, f);
    unsigned r = (u + 0x7fff + ((u >> 16) & 1)) >> 16;
    return (unsigned short)r;
}
__device__ __forceinline__ float b2f(unsigned short s) {
    return __builtin_bit_cast(float, (unsigned)s << 16);
}

// ---------------------------------------------------------------------------
// Weight prep: fp32 [COUT][CIN] -> bf16 [MP][KP], zero-padded, XOR-swizzled
// (byte ^= (row&7)<<4) so conv blocks can stage with a straight linear copy.
// ---------------------------------------------------------------------------
template<int CIN, int COUT>
__global__ void prep_w(const float* __restrict__ w, unsigned short* __restrict__ o_)
{
    constexpr int KP = (CIN > 64) ? 128 : 64;
    constexpr int MP = (COUT > 64) ? 128 : 64;
    const int i = blockIdx.x * 256 + threadIdx.x;
    if (i >= MP * KP) return;
    const int o = i / KP, c = i - o * KP;
    const float v = (o < COUT && c < CIN) ? w[o * CIN + c] : 0.f;
    o_[o * KP + (c ^ ((o & 7) << 3))] = f2b(v);
}

// shift5 source read (matches reference pad/slice directions)
template<int CIN, int GSH>
__device__ __forceinline__ float ld_shift(const float* __restrict__ in,
                                          int b, int h, int w, int c)
{
    if constexpr (GSH == 0) {
        return in[(b * CIN + c) * HW_ + h * W_ + w];
    } else {
        const int grp = c / GSH;
        const int dh = (grp == 2) ? 1 : ((grp == 3) ? -1 : 0);
        const int dw = (grp == 0) ? 1 : ((grp == 1) ? -1 : 0);
        const int h2 = h + dh, w2 = w + dw;
        if ((unsigned)h2 >= (unsigned)H_ || (unsigned)w2 >= (unsigned)W_) return 0.f;
        return in[(b * CIN + c) * HW_ + h2 * W_ + w2];
    }
}

// ---------------------------------------------------------------------------
// MFMA implicit-GEMM conv1x1 (+shift5 on load, +BN/ReLU/resid/extract epilogue)
// Block: 256 thr (4 waves), 64-pixel tile (one row segment -> h uniform).
// out[COUT x 64px] = W[COUT x K] * X^T[64px x K]^T via 16x16x32 bf16 MFMA.
// ---------------------------------------------------------------------------
template<int CIN, int COUT, int GSH, bool RELU, bool BN, bool RESID, bool EXTRACT>
__global__ __launch_bounds__(256)
void conv_mfma(const float* __restrict__ in, const unsigned short* __restrict__ wp,
               const float* __restrict__ bias,
               const float* __restrict__ bng, const float* __restrict__ bnb,
               const float* __restrict__ bnm, const float* __restrict__ bnv,
               const float* __restrict__ resid, float* __restrict__ out,
               unsigned short* __restrict__ q0)
{
    constexpr int KP  = (CIN  > 64) ? 128 : 64;
    constexpr int MP  = (COUT > 64) ? 128 : 64;
    constexpr int MT  = MP / 64;        // m-tiles per wave
    constexpr int KBL = KP / 32;        // mfma K-steps
    constexpr int KB2 = KP * 2;         // LDS row pitch bytes
    __shared__ unsigned short wlds[MP * KP];
    __shared__ unsigned short xlds[64 * KP];

    const int tid = threadIdx.x;
    const int n0  = blockIdx.x * 64;
    const int b   = n0 / HW_;
    const int p0  = n0 - b * HW_;
    const int hh  = p0 / W_;            // uniform per block
    const int ww0 = p0 - hh * W_;

    // stage weights: linear b128 copy of pre-swizzled bf16
    {
        const short8* src = (const short8*)wp;
        short8* dst = (short8*)wlds;
        constexpr int NV = MP * KP / 8;
        #pragma unroll
        for (int i = 0; i < NV / 256; ++i) dst[tid + 256 * i] = src[tid + 256 * i];
    }
    // stage X^T bf16, swizzled, shift5 applied. thread t: px=t&63, covers
    // even c-pairs {2*(t>>6) + 8i}.
    {
        const int px = tid & 63;
        const int w_ = ww0 + px;
        #pragma unroll
        for (int i = 0; i < KP / 8; ++i) {
            const int c = (tid >> 6) * 2 + i * 8;
            float v0 = 0.f, v1 = 0.f;
            if (c     < CIN) v0 = ld_shift<CIN, GSH>(in, b, hh, w_, c);
            if (c + 1 < CIN) v1 = ld_shift<CIN, GSH>(in, b, hh, w_, c + 1);
            const unsigned p01 = (unsigned)f2b(v0) | ((unsigned)f2b(v1) << 16);
            const int byte = px * KB2 + ((c * 2) ^ ((px & 7) << 4));
            *(unsigned*)((char*)xlds + byte) = p01;
        }
    }
    __syncthreads();

    const int wv = tid >> 6;
    const int lo = tid & 15;
    const int hi = (tid & 63) >> 4;

    f32x4 acc[MT][4];
    #pragma unroll
    for (int mt = 0; mt < MT; ++mt)
        #pragma unroll
        for (int nt = 0; nt < 4; ++nt) acc[mt][nt] = f32x4{0.f, 0.f, 0.f, 0.f};

    #pragma unroll
    for (int kb = 0; kb < KBL; ++kb) {
        short8 a[MT], bb[4];
        #pragma unroll
        for (int mt = 0; mt < MT; ++mt) {
            const int row  = (wv * MT + mt) * 16 + lo;
            const int byte = row * KB2 + ((kb * 64 + hi * 16) ^ ((row & 7) << 4));
            a[mt] = *(const short8*)((const char*)wlds + byte);
        }
        #pragma unroll
        for (int nt = 0; nt < 4; ++nt) {
            const int row  = nt * 16 + lo;
            const int byte = row * KB2 + ((kb * 64 + hi * 16) ^ ((row & 7) << 4));
            bb[nt] = *(const short8*)((const char*)xlds + byte);
        }
        #pragma unroll
        for (int mt = 0; mt < MT; ++mt)
            #pragma unroll
            for (int nt = 0; nt < 4; ++nt)
                acc[mt][nt] = __builtin_amdgcn_mfma_f32_16x16x32_bf16(
                    a[mt], bb[nt], acc[mt][nt], 0, 0, 0);
    }

    // epilogue: D col = lane&15 (px), row = (lane>>4)*4 + r (out-channel)
    #pragma unroll
    for (int mt = 0; mt < MT; ++mt) {
        const int m0 = (wv * MT + mt) * 16;
        #pragma unroll
        for (int nt = 0; nt < 4; ++nt) {
            const int px = p0 + nt * 16 + lo;
            #pragma unroll
            for (int r = 0; r < 4; ++r) {
                const int o = m0 + hi * 4 + r;
                if (o < COUT) {
                    float v = acc[mt][nt][r] + bias[o];
                    if (BN) v = (v - bnm[o]) * (bng[o] * rsqrtf(bnv[o] + 1e-5f)) + bnb[o];
                    if (RELU) v = fmaxf(v, 0.f);
                    const int oi = (b * COUT + o) * HW_ + px;
                    float vv = v;
                    if (RESID) vv += resid[oi];
                    out[oi] = vv;
                    if (EXTRACT) {
                        const int wi = o / 40, rr = o - wi * 40;
                        if (rr < 20) q0[(b * 60 + wi * 20 + rr) * HW_ + px] = f2b(vv);
                    }
                }
            }
        }
    }
}

// ---------------------------------------------------------------------------
// Window attention (unchanged from R1, plus bf16-q option for gmsa_shared).
// ---------------------------------------------------------------------------
template<int WS, int NW, bool QB>
__global__ __launch_bounds__(NW * WS * WS)
void attn_k(const void* __restrict__ qsrc_, int qC, int qbase,
            const float* __restrict__ vsrc, int vC, int vbase,
            float* __restrict__ out, int obase)
{
    constexpr int P     = WS * WS;
    constexpr int S     = WS / 2;
    constexpr int WGX   = W_ / WS;
    constexpr int WGY   = H_ / WS;
    constexpr int PITCH = 24;
    __shared__ float qt[NW * P * PITCH];
    __shared__ float vt[NW * P * PITCH];

    const int tid  = threadIdx.x;
    const int win  = tid / P;
    const int pos  = tid - win * P;
    const int gw   = blockIdx.x * NW + win;
    const int b    = gw / (WGY * WGX);
    const int rwin = gw - b * (WGY * WGX);
    const int wh   = rwin / WGX;
    const int ww   = rwin - wh * WGX;
    const int r    = pos / WS;
    const int c    = pos - r * WS;
    int hs = wh * WS + r + S; if (hs >= H_) hs -= H_;
    int wd = ww * WS + c + S; if (wd >= W_) wd -= W_;

    #pragma unroll
    for (int ch = 0; ch < 20; ++ch) {
        const long idx = (long)(b * qC + qbase + ch) * HW_ + hs * W_ + wd;
        float qv;
        if constexpr (QB) qv = b2f(((const unsigned short*)qsrc_)[idx]);
        else              qv = ((const float*)qsrc_)[idx];
        qt[(win * P + pos) * PITCH + ch] = qv;
    }
    #pragma unroll
    for (int ch = 0; ch < 20; ++ch)
        vt[(win * P + pos) * PITCH + ch] =
            vsrc[(b * vC + vbase + ch) * HW_ + hs * W_ + wd];
    __syncthreads();

    float qr[20];
    #pragma unroll
    for (int i = 0; i < 20; ++i) qr[i] = qt[(win * P + pos) * PITCH + i];

    float m = -INFINITY, lsum = 0.f;
    float acc[20];
    #pragma unroll
    for (int i = 0; i < 20; ++i) acc[i] = 0.f;

    for (int j = 0; j < P; ++j) {
        const float* qj = &qt[(win * P + j) * PITCH];
        float s = 0.f;
        #pragma unroll
        for (int i = 0; i < 20; ++i) s = fmaf(qr[i], qj[i], s);
        const float nm = fmaxf(m, s);
        const float f  = __expf(m - nm);
        const float e  = __expf(s - nm);
        lsum = lsum * f + e;
        const float* vj = &vt[(win * P + j) * PITCH];
        #pragma unroll
        for (int i = 0; i < 20; ++i) acc[i] = fmaf(e, vj[i], acc[i] * f);
        m = nm;
    }
    const float inv = 1.f / lsum;
    #pragma unroll
    for (int i = 0; i < 20; ++i)
        out[(b * 60 + obase + i) * HW_ + hs * W_ + wd] = acc[i] * inv;
}

// ---------------------------------------------------------------------------
extern "C" void kernel_launch(void* const* d_in, const int* in_sizes, int n_in,
                              void* d_out, int out_size, void* d_ws, size_t ws_size,
                              hipStream_t stream)
{
    const float* x     = (const float*)d_in[0];
    const float* l0w0  = (const float*)d_in[1];
    const float* l0b0  = (const float*)d_in[2];
    const float* l0w1  = (const float*)d_in[3];
    const float* l0b1  = (const float*)d_in[4];
    const float* g0piw = (const float*)d_in[5];
    const float* g0pib = (const float*)d_in[6];
    const float* g0bng = (const float*)d_in[7];
    const float* g0bnb = (const float*)d_in[8];
    const float* g0bnm = (const float*)d_in[9];
    const float* g0bnv = (const float*)d_in[10];
    const float* g0pow = (const float*)d_in[11];
    const float* g0pob = (const float*)d_in[12];
    const float* l1w0  = (const float*)d_in[13];
    const float* l1b0  = (const float*)d_in[14];
    const float* l1w1  = (const float*)d_in[15];
    const float* l1b1  = (const float*)d_in[16];
    const float* g1piw = (const float*)d_in[17];
    const float* g1pib = (const float*)d_in[18];
    const float* g1bng = (const float*)d_in[19];
    const float* g1bnb = (const float*)d_in[20];
    const float* g1bnm = (const float*)d_in[21];
    const float* g1bnv = (const float*)d_in[22];
    const float* g1pow = (const float*)d_in[23];
    const float* g1pob = (const float*)d_in[24];

    // ws layout: A (120ch f32) | CC (60ch f32) | Q0 (60ch bf16) | WP (bf16 weights)
    float* A  = (float*)d_ws;
    float* CC = A + NE_;
    unsigned short* Q0 = (unsigned short*)(CC + NC_);
    unsigned short* WP = Q0 + NC_;
    float* OUTF = (float*)d_out;

    unsigned short* W1  = WP;            // 128x64
    unsigned short* W2  = WP + 8192;     // 64x128
    unsigned short* W3  = WP + 16384;    // 128x64
    unsigned short* W5  = WP + 24576;    // 64x64
    unsigned short* W6  = WP + 28672;    // 128x64
    unsigned short* W7  = WP + 36864;    // 64x128
    unsigned short* W8  = WP + 45056;    // 64x64
    unsigned short* W10 = WP + 49152;    // 64x64

    prep_w<60, 120><<<32, 256, 0, stream>>>(l0w0,  W1);
    prep_w<120, 60><<<32, 256, 0, stream>>>(l0w1,  W2);
    prep_w<60, 120><<<32, 256, 0, stream>>>(g0piw, W3);
    prep_w<60, 60> <<<16, 256, 0, stream>>>(g0pow, W5);
    prep_w<60, 120><<<32, 256, 0, stream>>>(l1w0,  W6);
    prep_w<120, 60><<<32, 256, 0, stream>>>(l1w1,  W7);
    prep_w<60, 60> <<<16, 256, 0, stream>>>(g1piw, W8);
    prep_w<60, 60> <<<16, 256, 0, stream>>>(g1pow, W10);

    dim3 blk(256);
    dim3 gconv(B_ * HW_ / 64);     // 9216 blocks

    // S1: lfe0 hidden = relu(conv(shift5(x)))
    conv_mfma<60,120,12,true,false,false,false><<<gconv,blk,0,stream>>>(
        x, W1, l0b0, nullptr,nullptr,nullptr,nullptr, nullptr, A, nullptr);
    // S2: x1 = conv(shift5(hidden)) + x
    conv_mfma<120,60,24,false,false,true,false><<<gconv,blk,0,stream>>>(
        A, W2, l0b1, nullptr,nullptr,nullptr,nullptr, x, CC, nullptr);
    // S3: xp0 = BN(pi0(x1)); extract q-channels (bf16) into Q0
    conv_mfma<60,120,0,false,true,false,true><<<gconv,blk,0,stream>>>(
        CC, W3, g0pib, g0bng,g0bnb,g0bnm,g0bnv, nullptr, A, Q0);
    // S4: gmsa_first attention -> ys0 (d_out scratch)
    attn_k<4,16,false><<<dim3(36864/16),dim3(256),0,stream>>>(A,120,0,   A,120,20,  OUTF, 0);
    attn_k<8, 4,false><<<dim3( 9216/4 ),dim3(256),0,stream>>>(A,120,40,  A,120,60,  OUTF,20);
    attn_k<12,1,false><<<dim3( 4096   ),dim3(144),0,stream>>>(A,120,80,  A,120,100, OUTF,40);
    // S5: x2 = po0(ys0) + x1  (into CC)
    conv_mfma<60,60,0,false,false,true,false><<<gconv,blk,0,stream>>>(
        OUTF, W5, g0pob, nullptr,nullptr,nullptr,nullptr, CC, CC, nullptr);
    // S6: lfe1 hidden = relu(conv(shift5(x2)))
    conv_mfma<60,120,12,true,false,false,false><<<gconv,blk,0,stream>>>(
        CC, W6, l1b0, nullptr,nullptr,nullptr,nullptr, nullptr, A, nullptr);
    // S7: x3 = conv(shift5(hidden)) + x2  (into CC)
    conv_mfma<120,60,24,false,false,true,false><<<gconv,blk,0,stream>>>(
        A, W7, l1b1, nullptr,nullptr,nullptr,nullptr, CC, CC, nullptr);
    // S8: xp1 = BN(pi1(x3)) (into d_out scratch)
    conv_mfma<60,60,0,false,true,false,false><<<gconv,blk,0,stream>>>(
        CC, W8, g1pib, g1bng,g1bnb,g1bnm,g1bnv, nullptr, OUTF, nullptr);
    // S9: gmsa_shared attention (atn recomputed from bf16 Q0) -> ys1 (A)
    attn_k<4,16,true><<<dim3(36864/16),dim3(256),0,stream>>>(Q0,60,0,  OUTF,60,0,  A, 0);
    attn_k<8, 4,true><<<dim3( 9216/4 ),dim3(256),0,stream>>>(Q0,60,20, OUTF,60,20, A,20);
    attn_k<12,1,true><<<dim3( 4096   ),dim3(144),0,stream>>>(Q0,60,40, OUTF,60,40, A,40);
    // S10: out = po1(ys1) + x3
    conv_mfma<60,60,0,false,false,true,false><<<gconv,blk,0,stream>>>(
        A, W10, g1pob, nullptr,nullptr,nullptr,nullptr, CC, OUTF, nullptr);
}